// Round 10
// baseline (262.324 us; speedup 1.0000x reference)
//
#include <hip/hip_runtime.h>
#include <math.h>

// Problem constants (fixed shapes)
#define DIM    4096
#define NH     32
#define NKV    8
#define HD     128
#define BS     16
#define KVLEN  4096
#define LASTPOS 4095
#define QKV_COLS 6144   // 4096 q + 1024 k + 1024 v
#define NKC    64       // k-chunks for split-K projections

typedef float f32x4 __attribute__((ext_vector_type(4)));

// ws layout (floats):
//   qkv   : [16][6144]                @ 0        (98304)
//   attn  : [16][4096]                @ 98304    (65536)
//   part  : [8192 units][4][132]      @ 163840   (4325376)  unit = (block,wave)
//   pq    : [64][16][6144]            @ 4489216  (6291456)
//   pw    : [64][16][4096]            @ 10780672 (4194304)  end 14974976 (~60MB)
#define WS_QKV   0
#define WS_ATTN  98304
#define WS_PART  163840
#define WS_PQ    4489216
#define WS_PW    10780672

// ---------------------------------------------------------------------------
// K1a: qkv partials. block: 256 thr, 2 cols/thread (512 cols); grid (12, 64).
// ---------------------------------------------------------------------------
__global__ __launch_bounds__(256) void qkv_projA(
    const float* __restrict__ x, const float* __restrict__ wq,
    const float* __restrict__ wk, const float* __restrict__ wv,
    float* __restrict__ pq) {
  __shared__ float xs[16 * 64];
  const int tid = threadIdx.x;
  const int col = (blockIdx.x * 256 + tid) * 2;   // block-uniform matrix select
  const int kc = blockIdx.y;
  const int k0 = kc * 64;

  for (int i = tid; i < 1024; i += 256) {
    int b = i >> 6, k = i & 63;
    xs[i] = x[b * DIM + k0 + k];
  }
  __syncthreads();

  const float* w;
  int wstride, wcol;
  if (col < 4096)      { w = wq; wstride = 4096; wcol = col; }
  else if (col < 5120) { w = wk; wstride = 1024; wcol = col - 4096; }
  else                 { w = wv; wstride = 1024; wcol = col - 5120; }
  const float* wp = w + (size_t)k0 * wstride + wcol;

  float acc0[16], acc1[16];
#pragma unroll
  for (int b = 0; b < 16; ++b) { acc0[b] = 0.f; acc1[b] = 0.f; }

#pragma unroll 2
  for (int k = 0; k < 64; k += 4) {
    float2 w0 = *(const float2*)(wp + (size_t)(k + 0) * wstride);
    float2 w1 = *(const float2*)(wp + (size_t)(k + 1) * wstride);
    float2 w2 = *(const float2*)(wp + (size_t)(k + 2) * wstride);
    float2 w3 = *(const float2*)(wp + (size_t)(k + 3) * wstride);
#pragma unroll
    for (int b = 0; b < 16; ++b) {
      float4 xb = *(const float4*)(&xs[b * 64 + k]);
      acc0[b] += xb.x * w0.x + xb.y * w1.x + xb.z * w2.x + xb.w * w3.x;
      acc1[b] += xb.x * w0.y + xb.y * w1.y + xb.z * w2.y + xb.w * w3.y;
    }
  }
#pragma unroll
  for (int b = 0; b < 16; ++b) {
    *(float2*)(&pq[((size_t)kc * 16 + b) * QKV_COLS + col]) = make_float2(acc0[b], acc1[b]);
  }
}

// ---------------------------------------------------------------------------
// K1b: reduce 64 qkv partials + fused RoPE (+ q scale).
// ---------------------------------------------------------------------------
__global__ __launch_bounds__(256) void qkv_projB(
    const float* __restrict__ pq, float* __restrict__ qkv,
    const float* __restrict__ fc, const float* __restrict__ fs) {
  int t = blockIdx.x * 256 + threadIdx.x;       // 0..49151
  int b = t / 3072, pr = t % 3072;
  int col = 2 * pr;
  float e = 0.f, o = 0.f;
#pragma unroll 8
  for (int kc = 0; kc < NKC; ++kc) {
    float2 v = *(const float2*)(&pq[((size_t)kc * 16 + b) * QKV_COLS + col]);
    e += v.x; o += v.y;
  }
  float re = e, im = o;
  if (col < 5120) {  // q or k: rope
    int i = (col & 127) >> 1;
    float c = fc[i], s = fs[i];
    float scale = (col < 4096) ? 0.08838834764831845f : 1.0f;
    re = (e * c - o * s) * scale;
    im = (e * s + o * c) * scale;
  }
  *(float2*)(&qkv[b * QKV_COLS + col]) = make_float2(re, im);
}

// ---------------------------------------------------------------------------
// K3: attention — zero-LDS, register-lean, high-occupancy.
// Block = (bg, 256-row chunk), 256 thr = 4 independent waves; wave owns 64
// rows. Lane map: 64 lanes = 2 rows (p2) x 32 d-quads (ql): one f32x4 per
// lane covers a full 512B row-pair per load instruction (dense).
// Per 8-row batch: 4 K loads -> 16 dots -> 5-level shfl_xor butterfly (all
// lanes get all scores) -> online softmax (m[4],l[4],acc[4] in regs) -> 4 V
// loads -> PV with NO shuffles (lane owns its row's probs).
// ---------------------------------------------------------------------------
__global__ __launch_bounds__(256, 6) void attn_partial(
    const float* __restrict__ cache_k, const float* __restrict__ cache_v,
    const float* __restrict__ qkv, float* __restrict__ part) {
  const int tid = threadIdx.x;
  const int w = tid >> 6, lane = tid & 63;
  const int p2 = lane >> 5, ql = lane & 31;
  const int chunk = blockIdx.x & 15;
  const int bg = blockIdx.x >> 4;
  const int b = bg >> 3, g = bg & 7;
  const int t0 = chunk * 256 + w * 64;          // wave's first kv row

  // q regs: head h, d=[ql*4,+4)
  const float* qbase = qkv + b * QKV_COLS + g * 512;
  f32x4 qh[4];
#pragma unroll
  for (int h = 0; h < 4; ++h) qh[h] = *(const f32x4*)(qbase + h * 128 + ql * 4);

  const float* kw = cache_k + (size_t)b * 4194304 + g * 128 + (size_t)t0 * 1024;
  const float* vw = cache_v + (size_t)b * 4194304 + g * 128 + (size_t)t0 * 1024;
  const float* xk = qkv + b * QKV_COLS + 4096 + g * 128;
  const float* xv = qkv + b * QKV_COLS + 5120 + g * 128;

  float m[4], l[4];
  f32x4 acc[4];
#pragma unroll
  for (int h = 0; h < 4; ++h) { m[h] = -1e30f; l[h] = 0.f; acc[h] = (f32x4)(0.f); }

  const bool haslast = (t0 + 63 == LASTPOS);    // chunk 15, wave 3 only

  for (int bt = 0; bt < 8; ++bt) {
    const float* kb8 = kw + bt * 8192;
    f32x4 kf[4];
    if (!haslast || bt < 7) {
#pragma unroll
      for (int j = 0; j < 4; ++j)
        kf[j] = *(const f32x4*)(kb8 + (2 * j + p2) * 1024 + ql * 4);
    } else {
#pragma unroll
      for (int j = 0; j < 4; ++j) {
        int t = t0 + 56 + 2 * j + p2;
        const float* kr = (t == LASTPOS) ? xk : (kb8 + (2 * j + p2) * 1024);
        kf[j] = *(const f32x4*)(kr + ql * 4);
      }
    }

    // 16 dots: sv[j][h] = partial dot of row (2j+p2) with head h
    float sv[4][4];
#pragma unroll
    for (int j = 0; j < 4; ++j) {
#pragma unroll
      for (int h = 0; h < 4; ++h) {
        f32x4 pr = kf[j] * qh[h];
        sv[j][h] = pr[0] + pr[1] + pr[2] + pr[3];
      }
    }
    // butterfly reduce across the 32 d-lanes (stays within parity half)
#pragma unroll
    for (int off = 1; off < 32; off <<= 1) {
#pragma unroll
      for (int j = 0; j < 4; ++j) {
#pragma unroll
        for (int h = 0; h < 4; ++h)
          sv[j][h] += __shfl_xor(sv[j][h], off);
      }
    }

    // online softmax update per head
#pragma unroll
    for (int h = 0; h < 4; ++h) {
      float bm = fmaxf(fmaxf(sv[0][h], sv[1][h]), fmaxf(sv[2][h], sv[3][h]));
      bm = fmaxf(bm, __shfl_xor(bm, 32));      // combine the two parity halves
      float mn = fmaxf(m[h], bm);
      float f = __expf(m[h] - mn);
      m[h] = mn;
      acc[h] *= f;
#pragma unroll
      for (int j = 0; j < 4; ++j) sv[j][h] = __expf(sv[j][h] - mn);
      float ls = sv[0][h] + sv[1][h] + sv[2][h] + sv[3][h];
      ls += __shfl_xor(ls, 32);
      l[h] = l[h] * f + ls;
    }

    // V loads + PV (no shuffles: lane owns its row's probs)
    const float* vb8 = vw + bt * 8192;
    f32x4 vf[4];
    if (!haslast || bt < 7) {
#pragma unroll
      for (int j = 0; j < 4; ++j)
        vf[j] = *(const f32x4*)(vb8 + (2 * j + p2) * 1024 + ql * 4);
    } else {
#pragma unroll
      for (int j = 0; j < 4; ++j) {
        int t = t0 + 56 + 2 * j + p2;
        const float* vr = (t == LASTPOS) ? xv : (vb8 + (2 * j + p2) * 1024);
        vf[j] = *(const f32x4*)(vr + ql * 4);
      }
    }
#pragma unroll
    for (int j = 0; j < 4; ++j) {
#pragma unroll
      for (int h = 0; h < 4; ++h) acc[h] += sv[j][h] * vf[j];
    }
  }

  // combine parity halves of acc
#pragma unroll
  for (int h = 0; h < 4; ++h) {
#pragma unroll
    for (int k = 0; k < 4; ++k) acc[h][k] += __shfl_xor(acc[h][k], 32);
  }

  // write per-(block, wave, head) partial
  const size_t u = (size_t)blockIdx.x * 4 + w;   // unit = bg*64 + chunk*4 + w
  if (lane < 32) {
#pragma unroll
    for (int h = 0; h < 4; ++h)
      *(f32x4*)(&part[(u * 4 + h) * 132 + ql * 4]) = acc[h];
  }
  if (lane == 0) {
#pragma unroll
    for (int h = 0; h < 4; ++h) {
      part[(u * 4 + h) * 132 + 128] = m[h];
      part[(u * 4 + h) * 132 + 129] = l[h];
    }
  }
}

// ---------------------------------------------------------------------------
// K4: online-merge 64 unit-partials per (b,g,h,d) -> attn_out. 65536 thr.
// ---------------------------------------------------------------------------
__global__ __launch_bounds__(256) void attn_combine(
    const float* __restrict__ part, float* __restrict__ attn_out) {
  int t = blockIdx.x * 256 + threadIdx.x;   // 0..65535
  int d = t & 127, h = (t >> 7) & 3, g = (t >> 9) & 7, b = t >> 12;
  int bg = b * 8 + g;
  float M = -1e30f, num = 0.f, den = 0.f;
  for (int u = 0; u < 64; ++u) {
    const float* pr = part + ((size_t)(bg * 64 + u) * 4 + h) * 132;
    float mc = pr[128];
    float Mn = fmaxf(M, mc);
    float fo = __expf(M - Mn);
    float fcur = __expf(mc - Mn);
    num = num * fo + fcur * pr[d];
    den = den * fo + fcur * pr[129];
    M = Mn;
  }
  attn_out[b * DIM + (g * 4 + h) * 128 + d] = num / den;
}

// ---------------------------------------------------------------------------
// K5a: wo partials. block: 256 thr, 2 cols/thread (512 cols); grid (8, 64).
// ---------------------------------------------------------------------------
__global__ __launch_bounds__(256) void out_projA(
    const float* __restrict__ attn, const float* __restrict__ wo,
    float* __restrict__ pw) {
  __shared__ float xs[16 * 64];
  const int tid = threadIdx.x;
  const int col = (blockIdx.x * 256 + tid) * 2;  // 0..4094
  const int kc = blockIdx.y;
  const int k0 = kc * 64;

  for (int i = tid; i < 1024; i += 256) {
    int b = i >> 6, k = i & 63;
    xs[i] = attn[b * DIM + k0 + k];
  }
  __syncthreads();

  const float* wp = wo + (size_t)k0 * 4096 + col;
  float acc0[16], acc1[16];
#pragma unroll
  for (int b = 0; b < 16; ++b) { acc0[b] = 0.f; acc1[b] = 0.f; }

#pragma unroll 2
  for (int k = 0; k < 64; k += 4) {
    float2 w0 = *(const float2*)(wp + (size_t)(k + 0) * 4096);
    float2 w1 = *(const float2*)(wp + (size_t)(k + 1) * 4096);
    float2 w2 = *(const float2*)(wp + (size_t)(k + 2) * 4096);
    float2 w3 = *(const float2*)(wp + (size_t)(k + 3) * 4096);
#pragma unroll
    for (int b = 0; b < 16; ++b) {
      float4 xb = *(const float4*)(&xs[b * 64 + k]);
      acc0[b] += xb.x * w0.x + xb.y * w1.x + xb.z * w2.x + xb.w * w3.x;
      acc1[b] += xb.x * w0.y + xb.y * w1.y + xb.z * w2.y + xb.w * w3.y;
    }
  }
#pragma unroll
  for (int b = 0; b < 16; ++b) {
    *(float2*)(&pw[((size_t)kc * 16 + b) * DIM + col]) = make_float2(acc0[b], acc1[b]);
  }
}

// ---------------------------------------------------------------------------
// K5b: reduce 64 wo partials -> d_out.
// ---------------------------------------------------------------------------
__global__ __launch_bounds__(256) void out_projB(
    const float* __restrict__ pw, float* __restrict__ out) {
  int t = blockIdx.x * 256 + threadIdx.x;  // 65536
  int b = t >> 12, col = t & 4095;
  float sum = 0.f;
#pragma unroll 8
  for (int kc = 0; kc < NKC; ++kc)
    sum += pw[((size_t)kc * 16 + b) * DIM + col];
  out[b * DIM + col] = sum;
}

// ---------------------------------------------------------------------------
extern "C" void kernel_launch(void* const* d_in, const int* in_sizes, int n_in,
                              void* d_out, int out_size, void* d_ws, size_t ws_size,
                              hipStream_t stream) {
  const float* x  = (const float*)d_in[0];
  const float* wq = (const float*)d_in[1];
  const float* wk = (const float*)d_in[2];
  const float* wv = (const float*)d_in[3];
  const float* wo = (const float*)d_in[4];
  const float* ck = (const float*)d_in[5];
  const float* cv = (const float*)d_in[6];
  const float* fc = (const float*)d_in[7];
  const float* fs = (const float*)d_in[8];

  float* ws_f  = (float*)d_ws;
  float* qkv   = ws_f + WS_QKV;
  float* attn  = ws_f + WS_ATTN;
  float* part  = ws_f + WS_PART;
  float* pq    = ws_f + WS_PQ;
  float* pw    = ws_f + WS_PW;
  float* out   = (float*)d_out;

  qkv_projA<<<dim3(12, NKC), 256, 0, stream>>>(x, wq, wk, wv, pq);
  qkv_projB<<<192, 256, 0, stream>>>(pq, qkv, fc, fs);
  attn_partial<<<2048, 256, 0, stream>>>(ck, cv, qkv, part);
  attn_combine<<<256, 256, 0, stream>>>(part, attn);
  out_projA<<<dim3(8, NKC), 256, 0, stream>>>(attn, wo, pw);
  out_projB<<<256, 256, 0, stream>>>(pw, out);
}

// Round 11
// 205.392 us; speedup vs baseline: 1.2772x; 1.2772x over previous
//
#include <hip/hip_runtime.h>
#include <math.h>

// Problem constants (fixed shapes)
#define DIM    4096
#define NH     32
#define NKV    8
#define HD     128
#define BS     16
#define KVLEN  4096
#define LASTPOS 4095
#define QKV_COLS 6144   // 4096 q + 1024 k + 1024 v
#define NKC    64       // k-chunks for split-K projections

typedef float f32x4 __attribute__((ext_vector_type(4)));

// ws layout (floats):
//   qkv   : [16][6144]                @ 0        (98304)
//   attn  : [16][4096]                @ 98304    (65536)
//   part  : [8192 units][4][132]      @ 163840   (4325376)  unit = (block,wave)
//   pq    : [64][16][6144]            @ 4489216  (6291456)
//   pw    : [64][16][4096]            @ 10780672 (4194304)  end 14974976 (~60MB)
#define WS_QKV   0
#define WS_ATTN  98304
#define WS_PART  163840
#define WS_PQ    4489216
#define WS_PW    10780672

// ---------------------------------------------------------------------------
// K1a: qkv partials. block: 256 thr, 2 cols/thread (512 cols); grid (12, 64).
// ---------------------------------------------------------------------------
__global__ __launch_bounds__(256) void qkv_projA(
    const float* __restrict__ x, const float* __restrict__ wq,
    const float* __restrict__ wk, const float* __restrict__ wv,
    float* __restrict__ pq) {
  __shared__ float xs[16 * 64];
  const int tid = threadIdx.x;
  const int col = (blockIdx.x * 256 + tid) * 2;   // block-uniform matrix select
  const int kc = blockIdx.y;
  const int k0 = kc * 64;

  for (int i = tid; i < 1024; i += 256) {
    int b = i >> 6, k = i & 63;
    xs[i] = x[b * DIM + k0 + k];
  }
  __syncthreads();

  const float* w;
  int wstride, wcol;
  if (col < 4096)      { w = wq; wstride = 4096; wcol = col; }
  else if (col < 5120) { w = wk; wstride = 1024; wcol = col - 4096; }
  else                 { w = wv; wstride = 1024; wcol = col - 5120; }
  const float* wp = w + (size_t)k0 * wstride + wcol;

  float acc0[16], acc1[16];
#pragma unroll
  for (int b = 0; b < 16; ++b) { acc0[b] = 0.f; acc1[b] = 0.f; }

#pragma unroll 2
  for (int k = 0; k < 64; k += 4) {
    float2 w0 = *(const float2*)(wp + (size_t)(k + 0) * wstride);
    float2 w1 = *(const float2*)(wp + (size_t)(k + 1) * wstride);
    float2 w2 = *(const float2*)(wp + (size_t)(k + 2) * wstride);
    float2 w3 = *(const float2*)(wp + (size_t)(k + 3) * wstride);
#pragma unroll
    for (int b = 0; b < 16; ++b) {
      float4 xb = *(const float4*)(&xs[b * 64 + k]);
      acc0[b] += xb.x * w0.x + xb.y * w1.x + xb.z * w2.x + xb.w * w3.x;
      acc1[b] += xb.x * w0.y + xb.y * w1.y + xb.z * w2.y + xb.w * w3.y;
    }
  }
#pragma unroll
  for (int b = 0; b < 16; ++b) {
    *(float2*)(&pq[((size_t)kc * 16 + b) * QKV_COLS + col]) = make_float2(acc0[b], acc1[b]);
  }
}

// ---------------------------------------------------------------------------
// K1b: reduce 64 qkv partials + fused RoPE (+ q scale).
// ---------------------------------------------------------------------------
__global__ __launch_bounds__(256) void qkv_projB(
    const float* __restrict__ pq, float* __restrict__ qkv,
    const float* __restrict__ fc, const float* __restrict__ fs) {
  int t = blockIdx.x * 256 + threadIdx.x;       // 0..49151
  int b = t / 3072, pr = t % 3072;
  int col = 2 * pr;
  float e = 0.f, o = 0.f;
#pragma unroll 8
  for (int kc = 0; kc < NKC; ++kc) {
    float2 v = *(const float2*)(&pq[((size_t)kc * 16 + b) * QKV_COLS + col]);
    e += v.x; o += v.y;
  }
  float re = e, im = o;
  if (col < 5120) {  // q or k: rope
    int i = (col & 127) >> 1;
    float c = fc[i], s = fs[i];
    float scale = (col < 4096) ? 0.08838834764831845f : 1.0f;
    re = (e * c - o * s) * scale;
    im = (e * s + o * c) * scale;
  }
  *(float2*)(&qkv[b * QKV_COLS + col]) = make_float2(re, im);
}

// ---------------------------------------------------------------------------
// K3: attention — zero-LDS, register-lean, high-occupancy.
// Block = (bg, 256-row chunk), 256 thr = 4 independent waves; wave owns 64
// rows. Lane map: 64 lanes = 2 rows (p2) x 32 d-quads (ql): one f32x4 per
// lane covers a full 512B row-pair per load instruction (dense).
// Per 8-row batch: K AND V loads issued together (8 loads in flight) ->
// 16 dots -> 5-level shfl_xor butterfly -> online softmax (regs) -> PV with
// NO shuffles (lane owns its row's probs).
// NOTE: plain __launch_bounds__(256): a forced min-waves cap (R10: (256,6))
// pinned VGPR=40 against a ~110-reg live set -> 200+ MB scratch spill.
// ---------------------------------------------------------------------------
__global__ __launch_bounds__(256) void attn_partial(
    const float* __restrict__ cache_k, const float* __restrict__ cache_v,
    const float* __restrict__ qkv, float* __restrict__ part) {
  const int tid = threadIdx.x;
  const int w = tid >> 6, lane = tid & 63;
  const int p2 = lane >> 5, ql = lane & 31;
  const int chunk = blockIdx.x & 15;
  const int bg = blockIdx.x >> 4;
  const int b = bg >> 3, g = bg & 7;
  const int t0 = chunk * 256 + w * 64;          // wave's first kv row

  // q regs: head h, d=[ql*4,+4)
  const float* qbase = qkv + b * QKV_COLS + g * 512;
  f32x4 qh[4];
#pragma unroll
  for (int h = 0; h < 4; ++h) qh[h] = *(const f32x4*)(qbase + h * 128 + ql * 4);

  const float* kw = cache_k + (size_t)b * 4194304 + g * 128 + (size_t)t0 * 1024;
  const float* vw = cache_v + (size_t)b * 4194304 + g * 128 + (size_t)t0 * 1024;
  const float* xk = qkv + b * QKV_COLS + 4096 + g * 128;
  const float* xv = qkv + b * QKV_COLS + 5120 + g * 128;

  float m[4], l[4];
  f32x4 acc[4];
#pragma unroll
  for (int h = 0; h < 4; ++h) { m[h] = -1e30f; l[h] = 0.f; acc[h] = (f32x4)(0.f); }

  const bool haslast = (t0 + 63 == LASTPOS);    // chunk 15, wave 3 only

  for (int bt = 0; bt < 8; ++bt) {
    const float* kb8 = kw + bt * 8192;
    const float* vb8 = vw + bt * 8192;
    f32x4 kf[4], vf[4];
    if (!haslast || bt < 7) {
      // issue K and V together: 8 independent loads in flight per wave
#pragma unroll
      for (int j = 0; j < 4; ++j)
        kf[j] = *(const f32x4*)(kb8 + (2 * j + p2) * 1024 + ql * 4);
#pragma unroll
      for (int j = 0; j < 4; ++j)
        vf[j] = *(const f32x4*)(vb8 + (2 * j + p2) * 1024 + ql * 4);
    } else {
#pragma unroll
      for (int j = 0; j < 4; ++j) {
        int t = t0 + 56 + 2 * j + p2;
        const float* kr = (t == LASTPOS) ? xk : (kb8 + (2 * j + p2) * 1024);
        kf[j] = *(const f32x4*)(kr + ql * 4);
      }
#pragma unroll
      for (int j = 0; j < 4; ++j) {
        int t = t0 + 56 + 2 * j + p2;
        const float* vr = (t == LASTPOS) ? xv : (vb8 + (2 * j + p2) * 1024);
        vf[j] = *(const f32x4*)(vr + ql * 4);
      }
    }

    // 16 dots: sv[j][h] = partial dot of row (2j+p2) with head h
    float sv[4][4];
#pragma unroll
    for (int j = 0; j < 4; ++j) {
#pragma unroll
      for (int h = 0; h < 4; ++h) {
        f32x4 pr = kf[j] * qh[h];
        sv[j][h] = pr[0] + pr[1] + pr[2] + pr[3];
      }
    }
    // butterfly reduce across the 32 d-lanes (stays within parity half)
#pragma unroll
    for (int off = 1; off < 32; off <<= 1) {
#pragma unroll
      for (int j = 0; j < 4; ++j) {
#pragma unroll
        for (int h = 0; h < 4; ++h)
          sv[j][h] += __shfl_xor(sv[j][h], off);
      }
    }

    // online softmax update per head
#pragma unroll
    for (int h = 0; h < 4; ++h) {
      float bm = fmaxf(fmaxf(sv[0][h], sv[1][h]), fmaxf(sv[2][h], sv[3][h]));
      bm = fmaxf(bm, __shfl_xor(bm, 32));      // combine the two parity halves
      float mn = fmaxf(m[h], bm);
      float f = __expf(m[h] - mn);
      m[h] = mn;
      acc[h] *= f;
#pragma unroll
      for (int j = 0; j < 4; ++j) sv[j][h] = __expf(sv[j][h] - mn);
      float ls = sv[0][h] + sv[1][h] + sv[2][h] + sv[3][h];
      ls += __shfl_xor(ls, 32);
      l[h] = l[h] * f + ls;
    }

    // PV (no shuffles: lane owns its row's probs)
#pragma unroll
    for (int j = 0; j < 4; ++j) {
#pragma unroll
      for (int h = 0; h < 4; ++h) acc[h] += sv[j][h] * vf[j];
    }
  }

  // combine parity halves of acc
#pragma unroll
  for (int h = 0; h < 4; ++h) {
#pragma unroll
    for (int k = 0; k < 4; ++k) acc[h][k] += __shfl_xor(acc[h][k], 32);
  }

  // write per-(block, wave, head) partial
  const size_t u = (size_t)blockIdx.x * 4 + w;   // unit = bg*64 + chunk*4 + w
  if (lane < 32) {
#pragma unroll
    for (int h = 0; h < 4; ++h)
      *(f32x4*)(&part[(u * 4 + h) * 132 + ql * 4]) = acc[h];
  }
  if (lane == 0) {
#pragma unroll
    for (int h = 0; h < 4; ++h) {
      part[(u * 4 + h) * 132 + 128] = m[h];
      part[(u * 4 + h) * 132 + 129] = l[h];
    }
  }
}

// ---------------------------------------------------------------------------
// K4: online-merge 64 unit-partials per (b,g,h,d) -> attn_out. 65536 thr.
// ---------------------------------------------------------------------------
__global__ __launch_bounds__(256) void attn_combine(
    const float* __restrict__ part, float* __restrict__ attn_out) {
  int t = blockIdx.x * 256 + threadIdx.x;   // 0..65535
  int d = t & 127, h = (t >> 7) & 3, g = (t >> 9) & 7, b = t >> 12;
  int bg = b * 8 + g;
  float M = -1e30f, num = 0.f, den = 0.f;
  for (int u = 0; u < 64; ++u) {
    const float* pr = part + ((size_t)(bg * 64 + u) * 4 + h) * 132;
    float mc = pr[128];
    float Mn = fmaxf(M, mc);
    float fo = __expf(M - Mn);
    float fcur = __expf(mc - Mn);
    num = num * fo + fcur * pr[d];
    den = den * fo + fcur * pr[129];
    M = Mn;
  }
  attn_out[b * DIM + (g * 4 + h) * 128 + d] = num / den;
}

// ---------------------------------------------------------------------------
// K5a: wo partials. block: 256 thr, 2 cols/thread (512 cols); grid (8, 64).
// ---------------------------------------------------------------------------
__global__ __launch_bounds__(256) void out_projA(
    const float* __restrict__ attn, const float* __restrict__ wo,
    float* __restrict__ pw) {
  __shared__ float xs[16 * 64];
  const int tid = threadIdx.x;
  const int col = (blockIdx.x * 256 + tid) * 2;  // 0..4094
  const int kc = blockIdx.y;
  const int k0 = kc * 64;

  for (int i = tid; i < 1024; i += 256) {
    int b = i >> 6, k = i & 63;
    xs[i] = attn[b * DIM + k0 + k];
  }
  __syncthreads();

  const float* wp = wo + (size_t)k0 * 4096 + col;
  float acc0[16], acc1[16];
#pragma unroll
  for (int b = 0; b < 16; ++b) { acc0[b] = 0.f; acc1[b] = 0.f; }

#pragma unroll 2
  for (int k = 0; k < 64; k += 4) {
    float2 w0 = *(const float2*)(wp + (size_t)(k + 0) * 4096);
    float2 w1 = *(const float2*)(wp + (size_t)(k + 1) * 4096);
    float2 w2 = *(const float2*)(wp + (size_t)(k + 2) * 4096);
    float2 w3 = *(const float2*)(wp + (size_t)(k + 3) * 4096);
#pragma unroll
    for (int b = 0; b < 16; ++b) {
      float4 xb = *(const float4*)(&xs[b * 64 + k]);
      acc0[b] += xb.x * w0.x + xb.y * w1.x + xb.z * w2.x + xb.w * w3.x;
      acc1[b] += xb.x * w0.y + xb.y * w1.y + xb.z * w2.y + xb.w * w3.y;
    }
  }
#pragma unroll
  for (int b = 0; b < 16; ++b) {
    *(float2*)(&pw[((size_t)kc * 16 + b) * DIM + col]) = make_float2(acc0[b], acc1[b]);
  }
}

// ---------------------------------------------------------------------------
// K5b: reduce 64 wo partials -> d_out.
// ---------------------------------------------------------------------------
__global__ __launch_bounds__(256) void out_projB(
    const float* __restrict__ pw, float* __restrict__ out) {
  int t = blockIdx.x * 256 + threadIdx.x;  // 65536
  int b = t >> 12, col = t & 4095;
  float sum = 0.f;
#pragma unroll 8
  for (int kc = 0; kc < NKC; ++kc)
    sum += pw[((size_t)kc * 16 + b) * DIM + col];
  out[b * DIM + col] = sum;
}

// ---------------------------------------------------------------------------
extern "C" void kernel_launch(void* const* d_in, const int* in_sizes, int n_in,
                              void* d_out, int out_size, void* d_ws, size_t ws_size,
                              hipStream_t stream) {
  const float* x  = (const float*)d_in[0];
  const float* wq = (const float*)d_in[1];
  const float* wk = (const float*)d_in[2];
  const float* wv = (const float*)d_in[3];
  const float* wo = (const float*)d_in[4];
  const float* ck = (const float*)d_in[5];
  const float* cv = (const float*)d_in[6];
  const float* fc = (const float*)d_in[7];
  const float* fs = (const float*)d_in[8];

  float* ws_f  = (float*)d_ws;
  float* qkv   = ws_f + WS_QKV;
  float* attn  = ws_f + WS_ATTN;
  float* part  = ws_f + WS_PART;
  float* pq    = ws_f + WS_PQ;
  float* pw    = ws_f + WS_PW;
  float* out   = (float*)d_out;

  qkv_projA<<<dim3(12, NKC), 256, 0, stream>>>(x, wq, wk, wv, pq);
  qkv_projB<<<192, 256, 0, stream>>>(pq, qkv, fc, fs);
  attn_partial<<<2048, 256, 0, stream>>>(ck, cv, qkv, part);
  attn_combine<<<256, 256, 0, stream>>>(part, attn);
  out_projA<<<dim3(8, NKC), 256, 0, stream>>>(attn, wo, pw);
  out_projB<<<256, 256, 0, stream>>>(pw, out);
}